// Round 9
// baseline (150.707 us; speedup 1.0000x reference)
//
#include <hip/hip_runtime.h>
#include <math.h>

#define BLOCK 256
#define NN 100
#define NSLAB 64          // anchor slabs (blocks per image)
#define GA 4              // anchors per thread (slab = GA * BLOCK = 1024)
#define NPART (NSLAB * 4) // per-(b,n) column partials: 64 slabs x 4 waves
#define FLAG 0x40000000   // "override winner" marker in box_indice

__device__ __forceinline__ float fast_rcp(float x) { return __builtin_amdgcn_rcpf(x); }

// ---------------------------------------------------------------------------
// Single-pass match: block = (image, 1024-anchor slab). Each thread owns 4
// anchors (geometry in registers). Per box: 4 IoUs; row max thread-local
// (sole writer of row outputs — no pass A); column max thread-local over the
// 4 anchors then ONE u64 shfl wave-reduce per box (amortized 4x vs R5),
// per-wave partial plain-stored (no atomics, no barriers in hot loop).
// Exact first-argmax: ascending visit + strict >; cross-lane/slab ties via
// packed (iou<<32 | ~anchor) key.
// ---------------------------------------------------------------------------
__global__ void __launch_bounds__(BLOCK) bbp_match(
    const float* __restrict__ anchors,            // [A,4] cbox (cx,cy,w,h)
    const float* __restrict__ bboxes,             // [B,N,4] bbox
    float* __restrict__ max_iou_anchor,           // [B,A]
    int* __restrict__ box_indice,                 // [B,A]
    unsigned long long* __restrict__ packed_part, // [NPART][B*N] partial-major
    int A, int BN) {
    const int bid = blockIdx.x;
    const int b = bid >> 6;                 // / NSLAB
    const int slab = bid & (NSLAB - 1);
    const int tid = threadIdx.x;
    const int lane = tid & 63;
    const int wid = tid >> 6;
    const int abase = slab * (GA * BLOCK);

    // per-thread anchor geometry (registers)
    float ax1[GA], ay1[GA], ax2[GA], ay2[GA], aar[GA];
    #pragma unroll
    for (int g = 0; g < GA; ++g) {
        const int a = abase + g * BLOCK + tid;
        const float4 ac = *(const float4*)(anchors + (size_t)a * 4);
        ax1[g] = fmaf(ac.z, -0.5f, ac.x);
        ay1[g] = fmaf(ac.w, -0.5f, ac.y);
        ax2[g] = fmaf(ac.z, 0.5f, ac.x);
        ay2[g] = fmaf(ac.w, 0.5f, ac.y);
        aar[g] = ac.z * ac.w;
    }
    float best[GA];
    int bi[GA];
    #pragma unroll
    for (int g = 0; g < GA; ++g) { best[g] = -1.0f; bi[g] = 0; }

    const float* bbase = bboxes + (size_t)b * NN * 4;      // wave-uniform
    unsigned long long* pout =
        packed_part + ((size_t)(slab * 4 + wid)) * BN + (size_t)b * NN;

    #pragma unroll 2
    for (int n = 0; n < NN; ++n) {
        const float4 v = *(const float4*)(bbase + 4 * n);  // uniform -> s_load
        const float sa = (v.z - v.x) * (v.w - v.y);
        float cbest = -1.0f;
        unsigned ca = 0;
        #pragma unroll
        for (int g = 0; g < GA; ++g) {
            float lx = fmaxf(ax1[g], v.x), ly = fmaxf(ay1[g], v.y);
            float rx = fminf(ax2[g], v.z), ry = fminf(ay2[g], v.w);
            float w = fmaxf(rx - lx, 0.0f), h = fmaxf(ry - ly, 0.0f);
            float inter = w * h;
            float iou = inter * fast_rcp(aar[g] + sa - inter);
            if (iou > best[g]) { best[g] = iou; bi[g] = n; }       // row: first box
            if (iou > cbest) { cbest = iou; ca = (unsigned)(abase + g * BLOCK + tid); }
        }
        // column: one u64 wave-reduce per box (iou desc, anchor asc on ties)
        unsigned long long pk = ((unsigned long long)__float_as_uint(cbest) << 32)
                              | (unsigned long long)(0xFFFFFFFFu - ca);
        #pragma unroll
        for (int off = 32; off > 0; off >>= 1) {
            unsigned long long o = __shfl_down(pk, off, 64);
            if (o > pk) pk = o;
        }
        if (lane == 0) pout[n] = pk;
    }

    // row outputs: sole writer
    #pragma unroll
    for (int g = 0; g < GA; ++g) {
        const size_t idx = (size_t)b * A + abase + g * BLOCK + tid;
        max_iou_anchor[idx] = best[g];
        box_indice[idx] = bi[g];
    }
}

// ---------------------------------------------------------------------------
// Combine: reduce NPART partials -> packed; fused override scatter into
// box_indice via atomicMax(n | FLAG). Coalesced: partial-major layout.
// ---------------------------------------------------------------------------
__global__ void __launch_bounds__(BLOCK) bbp_combine(
    const unsigned long long* __restrict__ packed_part,  // [NPART][BN]
    unsigned long long* __restrict__ packed,             // [BN]
    int* __restrict__ box_indice,                        // [B,A]
    int A, int BN) {
    int i = blockIdx.x * BLOCK + threadIdx.x;
    if (i >= BN) return;
    unsigned long long m = 0ull;
    #pragma unroll 8
    for (int p = 0; p < NPART; ++p) {
        unsigned long long o = packed_part[(size_t)p * BN + i];
        if (o > m) m = o;
    }
    packed[i] = m;
    int b = i / NN;
    int n = i - b * NN;
    unsigned an = 0xFFFFFFFFu - (unsigned)(m & 0xFFFFFFFFull);
    atomicMax(&box_indice[(size_t)b * A + an], n | FLAG);
}

// ---------------------------------------------------------------------------
// Finalize: decode override flag, score, one-hot conf, delta encoding.
// ---------------------------------------------------------------------------
__global__ void __launch_bounds__(BLOCK) bbp_finalize(
    const float* __restrict__ anchors, const float* __restrict__ bboxes,
    const int* __restrict__ labels, const float* __restrict__ mean4,
    const float* __restrict__ std4, const float* __restrict__ thr_p,
    const float* __restrict__ max_iou_anchor, const int* __restrict__ box_indice,
    const unsigned long long* __restrict__ packed,
    float* __restrict__ out_conf, float* __restrict__ out_deltas,
    int A, int N, int C) {
    const int b = blockIdx.y;
    const int a = blockIdx.x * BLOCK + threadIdx.x;
    if (a >= A) return;
    const float thr = thr_p[0];
    const size_t idx = (size_t)b * A + a;

    int w = box_indice[idx];
    bool valid = (w >= FLAG);
    int bi = valid ? (w & (FLAG - 1)) : w;
    unsigned long long pk = packed[(size_t)b * N + bi];
    float mb = __uint_as_float((unsigned)(pk >> 32));   // max_iou_of_bbox[bi]
    float miou = valid ? mb : max_iou_anchor[idx];
    float denom = fmaxf(mb, thr);
    if (miou < thr * 0.5f) miou = 0.0f;
    float score = miou * fast_rcp(denom);
    int lab = labels[(size_t)b * N + bi];
    if (lab <= 0) { score = 0.0f; lab = 0; }

    for (int c = 0; c < C; ++c)
        out_conf[idx * C + c] = (lab == c + 1) ? score : 0.0f;

    float4 bb = *(const float4*)(bboxes + ((size_t)b * N + bi) * 4);
    float4 ac = *(const float4*)(anchors + (size_t)a * 4);
    float cx = (bb.x + bb.z) * 0.5f;
    float cy = (bb.y + bb.w) * 0.5f;
    float bw = bb.z - bb.x;
    float bh = bb.w - bb.y;
    const float rz = fast_rcp(ac.z), rw = fast_rcp(ac.w);
    float4 d;
    d.x = ((cx - ac.x) * rz - mean4[0]) * fast_rcp(std4[0]);
    d.y = ((cy - ac.y) * rw - mean4[1]) * fast_rcp(std4[1]);
    d.z = (__logf(bw * rz) - mean4[2]) * fast_rcp(std4[2]);
    d.w = (__logf(bh * rw) - mean4[3]) * fast_rcp(std4[3]);
    *(float4*)(out_deltas + idx * 4) = d;
}

// ---------------------------------------------------------------------------
extern "C" void kernel_launch(void* const* d_in, const int* in_sizes, int n_in,
                              void* d_out, int out_size, void* d_ws, size_t ws_size,
                              hipStream_t stream) {
    const float* anchors = (const float*)d_in[0];
    const int* labels = (const int*)d_in[1];
    const float* bboxes = (const float*)d_in[2];
    const float* mean4 = (const float*)d_in[3];
    const float* std4 = (const float*)d_in[4];
    const float* thr_p = (const float*)d_in[5];

    const int A = in_sizes[0] / 4;        // 65536
    const int BN = in_sizes[1];           // 800
    const int N = NN;                     // 100
    const int B = BN / N;                 // 8
    const int C = out_size / (B * A) - 4; // 1

    char* ws = (char*)d_ws;
    unsigned long long* packed_part = (unsigned long long*)ws;  // [NPART*BN] = 1.6 MB
    size_t off = ((size_t)NPART * BN * sizeof(unsigned long long) + 255) & ~(size_t)255;
    unsigned long long* packed = (unsigned long long*)(ws + off);
    off += ((size_t)BN * sizeof(unsigned long long) + 255) & ~(size_t)255;
    float* max_iou_anchor = (float*)(ws + off); off += (size_t)B * A * sizeof(float);
    off = (off + 255) & ~(size_t)255;
    int* box_indice = (int*)(ws + off);

    float* out_conf = (float*)d_out;
    float* out_deltas = out_conf + (size_t)B * A * C;

    bbp_match<<<dim3(B * NSLAB), dim3(BLOCK), 0, stream>>>(
        anchors, bboxes, max_iou_anchor, box_indice, packed_part, A, BN);

    bbp_combine<<<dim3((BN + BLOCK - 1) / BLOCK), dim3(BLOCK), 0, stream>>>(
        packed_part, packed, box_indice, A, BN);

    dim3 grid(A / BLOCK, B);
    bbp_finalize<<<grid, dim3(BLOCK), 0, stream>>>(anchors, bboxes, labels, mean4, std4,
                                                   thr_p, max_iou_anchor, box_indice,
                                                   packed, out_conf, out_deltas,
                                                   A, N, C);
}